// Round 2
// baseline (1145.537 us; speedup 1.0000x reference)
//
#include <hip/hip_runtime.h>
#include <hip/hip_fp16.h>
#include <hip/hip_cooperative_groups.h>

namespace cg = cooperative_groups;

#define B_ 256
#define V_ 1000
#define P_ 200
#define L_ 50
#define H_ 384
#define H3_ 1152
#define NW_ 10
#define OUT1_OFF 12800000

typedef _Float16 half8 __attribute__((ext_vector_type(8)));
typedef _Float16 half4_t __attribute__((ext_vector_type(4)));
typedef float floatx4 __attribute__((ext_vector_type(4)));

// ---------------------------------------------------------------------------
// prep: f16 weight conversions, h0 init, gate softmax, output-1 write.
// ---------------------------------------------------------------------------
__global__ __launch_bounds__(256) void prep_kernel(
    const float* __restrict__ gate_emb, const float* __restrict__ prog_emb,
    const float* __restrict__ sk, const float* __restrict__ w_ih,
    const float* __restrict__ w_hh, const int* __restrict__ instr,
    const int* __restrict__ tacts,
    float* __restrict__ h0, float* __restrict__ g01,
    _Float16* __restrict__ whh_h, _Float16* __restrict__ wih_h,
    _Float16* __restrict__ prog_h, float* __restrict__ out)
{
  const int stride = gridDim.x * blockDim.x;
  const int tid = blockIdx.x * blockDim.x + threadIdx.x;

  for (int i = tid; i < H3_*H_; i += stride) whh_h[i] = (_Float16)w_hh[i];
  for (int i = tid; i < H3_*224; i += stride) {
    int r = i / 224, c = i - r*224;
    wih_h[i] = (_Float16)(c < P_ ? w_ih[r*P_ + c] : 0.f);  // zero-pad K to 224
  }
  for (int i = tid; i < V_*P_; i += stride) prog_h[i] = (_Float16)prog_emb[i];
  for (int i = tid; i < B_*H_; i += stride) h0[i] = sk[(i % H_) & 127];
  for (int i = tid; i < NW_*B_; i += stride) {
    int w = i / B_, b = i - w*B_;
    int word = instr[(1+w)*B_ + b];
    float e0 = gate_emb[word*2], e1 = gate_emb[word*2+1];
    float m = fmaxf(e0, e1);
    float a = __expf(e0-m), c = __expf(e1-m);
    float inv = 1.f/(a+c);
    g01[i*2] = a*inv; g01[i*2+1] = c*inv;
  }
  for (int i = tid; i < B_*L_; i += stride) {
    int b = i / L_, l = i - b*L_;
    out[OUT1_OFF + i] = (float)tacts[(1+l)*B_ + b];
  }
}

// ---------------------------------------------------------------------------
// gi_gemm: giv[v][n] = program_emb[v] @ w_ih.T + b_ih   (vocab-wide, once)
// ---------------------------------------------------------------------------
__global__ __launch_bounds__(256) void gi_gemm(
    const _Float16* __restrict__ prog_h, const _Float16* __restrict__ wih_h,
    const float* __restrict__ b_ih, float* __restrict__ giv)
{
  __shared__ _Float16 pA[16][232];
  const int tid = threadIdx.x;
  const int v0 = blockIdx.x * 16;
  const int n0 = blockIdx.y * 64;

  for (int i = tid; i < 16*224; i += 256) {
    int r = i / 224, c = i - r*224;
    int v = v0 + r;
    _Float16 val = (_Float16)0.f;
    if (v < V_ && c < P_) val = prog_h[v*P_ + c];
    pA[r][c] = val;
  }
  __syncthreads();

  const int wave = tid >> 6, lane = tid & 63;
  const int m = lane & 15, kg = lane >> 4;
  const int n_t = n0 + wave*16;
  floatx4 acc = {0.f, 0.f, 0.f, 0.f};
  #pragma unroll
  for (int ks = 0; ks < 7; ++ks) {
    const int kk = ks*32 + kg*8;
    half8 av = *(const half8*)&pA[m][kk];
    half8 bv = *(const half8*)&wih_h[(n_t + m)*224 + kk];
    acc = __builtin_amdgcn_mfma_f32_16x16x32_f16(av, bv, acc, 0, 0, 0);
  }
  const int nn = n_t + (lane & 15);
  const float bias = b_ih[nn];
  #pragma unroll
  for (int r = 0; r < 4; ++r) {
    int mm = v0 + kg*4 + r;
    if (mm < V_) giv[(size_t)mm*H3_ + nn] = acc[r] + bias;
  }
}

// ---------------------------------------------------------------------------
// steps: persistent cooperative kernel, all 30 recurrence steps.
// Block bid: GEMM k-slice (bid&15)*24 for b-group (bid>>4)*16; attention + S
// for b_own = bid.  w_hh slice, b_hh slice, per-word gi slice, and S coeffs
// live in LDS for the whole kernel.  One grid.sync() per step (h exchange).
// ---------------------------------------------------------------------------
__global__ __launch_bounds__(512, 1) void steps_kernel(
    float* __restrict__ h_buf, float* __restrict__ S_buf,
    const _Float16* __restrict__ whh_h, const float* __restrict__ giv,
    const float* __restrict__ g01, const float* __restrict__ keys,
    const float* __restrict__ b_hh, const int* __restrict__ instr)
{
  __shared__ _Float16 whh[72][392];   // weight slice (pad 8 -> 2-way max)
  __shared__ _Float16 hT[16][392];
  __shared__ float ghT[16][80];
  __shared__ float Srow[50][12];
  __shared__ float gis[16][72];
  __shared__ float bhh[72];
  __shared__ float wmm[50];
  __shared__ float nv[12];
  __shared__ int   wordid[16];
  __shared__ float g0s[16], g1s[16];

  cg::grid_group gridg = cg::this_grid();

  const int bid   = blockIdx.x;
  const int slice = bid & 15;
  const int b0    = (bid >> 4) << 4;
  const int b_own = bid;
  const int k0    = slice * 24;
  const int tid   = threadIdx.x;
  const int wave  = tid >> 6;
  const int lane  = tid & 63;

  // one-time staging: weight slice rows r -> global row (r/24)*384 + k0 + r%24
  for (int i = tid; i < 72*48; i += 512) {
    int r = i / 48, c8 = i - r*48;
    int grow = (r/24)*H_ + k0 + (r - (r/24)*24);
    *(half8*)&whh[r][c8*8] = *(const half8*)&whh_h[(size_t)grow*H_ + c8*8];
  }
  for (int i = tid; i < 600; i += 512) Srow[i/12][i%12] = ((i%12) == 0) ? 1.f : 0.f;
  if (tid < 72) bhh[tid] = b_hh[(tid/24)*H_ + k0 + (tid%24)];

  for (int t = 0; t < 30; ++t) {
    const int widx = t / 3;
    float* h_cur = h_buf + (size_t)(t & 1)*(B_*H_);
    float* h_nxt = h_buf + (size_t)((t+1) & 1)*(B_*H_);

    if ((t % 3) == 0) {
      if (tid < 16) {
        wordid[tid] = instr[(1+widx)*B_ + b0 + tid];
        g0s[tid] = g01[(widx*B_ + b0 + tid)*2 + 0];
        g1s[tid] = g01[(widx*B_ + b0 + tid)*2 + 1];
      }
      __syncthreads();
      for (int i = tid; i < 16*72; i += 512) {
        int bl = i / 72, r = i - bl*72;
        gis[bl][r] = giv[(size_t)wordid[bl]*H3_ + (r/24)*H_ + k0 + (r - (r/24)*24)];
      }
    }

    // stage h tile (f32 -> f16), vectorized
    for (int i = tid; i < 16*96; i += 512) {
      int bl = i / 96, k4 = (i - bl*96)*4;
      float4 v = *(const float4*)&h_cur[(size_t)(b0+bl)*H_ + k4];
      half4_t hv = {(_Float16)v.x, (_Float16)v.y, (_Float16)v.z, (_Float16)v.w};
      *(half4_t*)&hT[bl][k4] = hv;
    }
    __syncthreads();

    if (wave < 5) {
      // GEMM: 5 waves x one 16-col tile (cols 0..79, valid < 72)
      const int m  = lane & 15;
      const int kg = lane >> 4;
      const int ncol = wave*16 + m;
      const int ncl  = ncol < 72 ? ncol : 71;
      floatx4 acc = {0.f, 0.f, 0.f, 0.f};
      #pragma unroll
      for (int ks = 0; ks < 12; ++ks) {
        const int kk = ks*32 + kg*8;
        half8 av = *(const half8*)&hT[m][kk];
        half8 bv = *(const half8*)&whh[ncl][kk];
        acc = __builtin_amdgcn_mfma_f32_16x16x32_f16(av, bv, acc, 0, 0, 0);
      }
      if (ncol < 72) {
        #pragma unroll
        for (int r = 0; r < 4; ++r) ghT[kg*4 + r][ncol] = acc[r];
      }
    } else if (wave < 7) {
      // wave 5: read_p -> read_attn -> nv ; wave 6: write_p -> wmm
      const float* __restrict__ hp = h_cur + (size_t)b_own*H_ + (wave == 5 ? 128 : 256);
      float val = 0.f;
      if (lane < 50) {
        const float4* __restrict__ hp4 = (const float4*)hp;
        const float4* __restrict__ kr4 = (const float4*)(keys + lane*128);
        float s0=0.f, s1=0.f, s2=0.f, s3=0.f;
        #pragma unroll
        for (int k = 0; k < 32; ++k) {
          float4 a = hp4[k], bq = kr4[k];
          s0 += a.x*bq.x; s1 += a.y*bq.y; s2 += a.z*bq.z; s3 += a.w*bq.w;
        }
        val = (s0+s1)+(s2+s3);
      }
      float mx = lane < 50 ? val : -1e30f;
      #pragma unroll
      for (int off = 32; off; off >>= 1) mx = fmaxf(mx, __shfl_xor(mx, off));
      float e = lane < 50 ? __expf(val - mx) : 0.f;
      float sm = e;
      #pragma unroll
      for (int off = 32; off; off >>= 1) sm += __shfl_xor(sm, off);
      float p = e / sm;
      if (wave == 6) {
        if (lane < 50) wmm[lane] = p;
      } else {
        const int jj = lane < 12 ? lane : 0;
        float rv = 0.f;
        for (int l = 0; l < 50; ++l) {
          float pl = __shfl(p, l);
          rv += pl * Srow[l][jj];
        }
        if (lane < 11) {
          nv[lane] = g1s[slice]*rv + (lane == (1+widx) ? g0s[slice] : 0.f);
        }
      }
    }
    __syncthreads();

    // S-coefficient update (in LDS, in place)
    for (int i = tid; i < 550; i += 512) {
      const int l = i / 11, j = i - l*11;
      const float wv = wmm[l];
      Srow[l][j] = wv*nv[j] + (1.f - wv)*Srow[l][j];
    }

    // GRU gate epilogue + word-gated h update
    for (int i = tid; i < 384; i += 512) {
      const int bl = i / 24, k = i - bl*24;
      const int kk = k0 + k;
      const float gh0 = ghT[bl][k]    + bhh[k];
      const float gh1 = ghT[bl][24+k] + bhh[24+k];
      const float gh2 = ghT[bl][48+k] + bhh[48+k];
      const float r  = 1.f/(1.f + __expf(-(gis[bl][k]    + gh0)));
      const float z  = 1.f/(1.f + __expf(-(gis[bl][24+k] + gh1)));
      const float x2 = gis[bl][48+k] + r*gh2;
      const float nn = 2.f/(1.f + __expf(-2.f*x2)) - 1.f;   // tanh
      const float hold = h_cur[(size_t)(b0+bl)*H_ + kk];
      const float hnew = (1.f - z)*nn + z*hold;
      h_nxt[(size_t)(b0+bl)*H_ + kk] = g0s[bl]*hold + g1s[bl]*hnew;
    }
    gridg.sync();
  }

  // spill S coefficients for epilogue kernels
  for (int i = tid; i < 600; i += 512) S_buf[(size_t)b_own*600 + i] = Srow[i/12][i%12];
}

// ---------------------------------------------------------------------------
// lse: per (b,l) log-sum-exp over the 1000-v reconstruction.
// ---------------------------------------------------------------------------
__global__ __launch_bounds__(512) void lse_kernel(
    const float* __restrict__ S_buf, const float* __restrict__ prim_emb,
    const float* __restrict__ iv_g, const int* __restrict__ instr,
    float* __restrict__ ls_buf)
{
  __shared__ float prim[10][1000];
  __shared__ float iv[1000];
  __shared__ float Sr[50][12];
  __shared__ int wds[10];

  const int b = blockIdx.x;
  const int tid = threadIdx.x;

  if (tid < 10) wds[tid] = instr[(1+tid)*B_ + b];
  for (int i = tid; i < 600; i += 512) Sr[i/12][i%12] = S_buf[(size_t)b*600 + i];
  __syncthreads();
  for (int wi = 0; wi < 10; ++wi) {
    const float4* __restrict__ src = (const float4*)(prim_emb + (size_t)wds[wi]*V_);
    for (int i = tid; i < 250; i += 512) ((float4*)prim[wi])[i] = src[i];
  }
  for (int i = tid; i < 250; i += 512) ((float4*)iv)[i] = ((const float4*)iv_g)[i];
  __syncthreads();

  const int wave = tid >> 6, lane = tid & 63;
  for (int l = wave; l < L_; l += 8) {
    float c0 = Sr[l][0];
    float cw[10];
    #pragma unroll
    for (int wi = 0; wi < 10; ++wi) cw[wi] = Sr[l][1+wi];
    float sv[16];
    float mx = -1e30f;
    #pragma unroll
    for (int j = 0; j < 16; ++j) {
      int v = lane + 64*j;
      float s = -1e30f;
      if (v < V_) {
        s = c0 * iv[v];
        #pragma unroll
        for (int wi = 0; wi < 10; ++wi) s += cw[wi]*prim[wi][v];
      }
      sv[j] = s;
      mx = fmaxf(mx, s);
    }
    #pragma unroll
    for (int off = 32; off; off >>= 1) mx = fmaxf(mx, __shfl_xor(mx, off));
    float se = 0.f;
    #pragma unroll
    for (int j = 0; j < 16; ++j) {
      int v = lane + 64*j;
      if (v < V_) se += __expf(sv[j] - mx);
    }
    #pragma unroll
    for (int off = 32; off; off >>= 1) se += __shfl_xor(se, off);
    if (lane == 0) ls_buf[b*L_ + l] = mx + __logf(se);
  }
}

// ---------------------------------------------------------------------------
// write: per (v-chunk of 125, b) block computes sv - lse and stores a
// contiguous 25 KB region (fully coalesced).
// ---------------------------------------------------------------------------
__global__ __launch_bounds__(256) void write_kernel(
    const float* __restrict__ S_buf, const float* __restrict__ prim_emb,
    const float* __restrict__ iv_g, const float* __restrict__ ls_buf,
    const int* __restrict__ instr, float* __restrict__ out)
{
  __shared__ float SrT[11][52];
  __shared__ float lss[52];
  __shared__ float primc[10][128];
  __shared__ float ivc[128];
  __shared__ int wds[10];

  const int cx = blockIdx.x;      // 0..7
  const int b  = blockIdx.y;      // 0..255
  const int v0 = cx * 125;
  const int tid = threadIdx.x;

  if (tid < 10) wds[tid] = instr[(1+tid)*B_ + b];
  if (tid < 50) lss[tid] = ls_buf[b*L_ + tid];
  for (int i = tid; i < 550; i += 256) {
    int l = i / 11, j = i - l*11;
    SrT[j][l] = S_buf[(size_t)b*600 + l*12 + j];
  }
  for (int i = tid; i < 125; i += 256) ivc[i] = iv_g[v0 + i];
  __syncthreads();
  for (int i = tid; i < 1250; i += 256) {
    int wi = i / 125, j = i - wi*125;
    primc[wi][j] = prim_emb[(size_t)wds[wi]*V_ + v0 + j];
  }
  __syncthreads();

  float* __restrict__ dst = out + (size_t)b*50000 + (size_t)v0*50;
  for (int e = tid; e < 125*50; e += 256) {
    const int v = e / 50, l = e - v*50;
    float s = SrT[0][l]*ivc[v];
    #pragma unroll
    for (int wi = 0; wi < 10; ++wi) s += SrT[1+wi][l]*primc[wi][v];
    dst[e] = s - lss[l];
  }
}

// ---------------------------------------------------------------------------
extern "C" void kernel_launch(void* const* d_in, const int* in_sizes, int n_in,
                              void* d_out, int out_size, void* d_ws, size_t ws_size,
                              hipStream_t stream)
{
  (void)in_sizes; (void)n_in; (void)out_size; (void)ws_size;
  const float* gate_emb = (const float*)d_in[0];
  const float* prog_emb = (const float*)d_in[1];
  const float* prim_emb = (const float*)d_in[2];
  const float* sk       = (const float*)d_in[3];
  const float* iv       = (const float*)d_in[4];
  const float* w_ih     = (const float*)d_in[5];
  const float* w_hh     = (const float*)d_in[6];
  const float* b_ih     = (const float*)d_in[7];
  const float* b_hh     = (const float*)d_in[8];
  const int*   instr    = (const int*)d_in[9];
  const int*   tacts    = (const int*)d_in[10];
  float* out = (float*)d_out;

  float* ws     = (float*)d_ws;
  float* h_buf  = ws;                        // 2*256*384 f32
  float* S_buf  = h_buf + 2*B_*H_;           // 256*600 f32
  float* g01    = S_buf + B_*600;            // 5120 f32
  float* ls_buf = g01 + NW_*B_*2;            // 256*50 f32
  float* giv    = ls_buf + B_*L_;            // 1000*1152 f32
  _Float16* whh_h  = (_Float16*)(giv + (size_t)V_*H3_);
  _Float16* wih_h  = whh_h + (size_t)H3_*H_;
  _Float16* prog_h = wih_h + (size_t)H3_*224;

  hipLaunchKernelGGL(prep_kernel, dim3(1024), dim3(256), 0, stream,
      gate_emb, prog_emb, sk, w_ih, w_hh, instr, tacts,
      h_buf, g01, whh_h, wih_h, prog_h, out);

  hipLaunchKernelGGL(gi_gemm, dim3(63, 18), dim3(256), 0, stream,
      prog_h, wih_h, b_ih, giv);

  {
    float* hb = h_buf; float* sb = S_buf;
    const _Float16* wh = whh_h; const float* gv = giv; const float* gg = g01;
    const float* ky = sk; const float* bh = b_hh; const int* in_ = instr;
    void* args[] = { (void*)&hb, (void*)&sb, (void*)&wh, (void*)&gv,
                     (void*)&gg, (void*)&ky, (void*)&bh, (void*)&in_ };
    hipLaunchCooperativeKernel((void*)steps_kernel, dim3(256), dim3(512),
                               args, 0, stream);
  }

  hipLaunchKernelGGL(lse_kernel, dim3(256), dim3(512), 0, stream,
      S_buf, prim_emb, iv, instr, ls_buf);

  hipLaunchKernelGGL(write_kernel, dim3(8, 256), dim3(256), 0, stream,
      S_buf, prim_emb, iv, ls_buf, instr, out);
}

// Round 3
// 886.852 us; speedup vs baseline: 1.2917x; 1.2917x over previous
//
#include <hip/hip_runtime.h>
#include <hip/hip_fp16.h>

#define B_ 256
#define V_ 1000
#define P_ 200
#define L_ 50
#define H_ 384
#define H3_ 1152
#define NW_ 10
#define OUT1_OFF 12800000

typedef _Float16 half8 __attribute__((ext_vector_type(8)));
typedef _Float16 half4_t __attribute__((ext_vector_type(4)));
typedef float floatx4 __attribute__((ext_vector_type(4)));

// ---------------------------------------------------------------------------
// prep: f16 weight conversions, gate softmax, output-1 write.
// ---------------------------------------------------------------------------
__global__ __launch_bounds__(256) void prep_kernel(
    const float* __restrict__ gate_emb, const float* __restrict__ prog_emb,
    const float* __restrict__ w_ih, const float* __restrict__ w_hh,
    const int* __restrict__ instr, const int* __restrict__ tacts,
    float* __restrict__ g01,
    _Float16* __restrict__ whh_h, _Float16* __restrict__ wih_h,
    _Float16* __restrict__ prog_h, float* __restrict__ out)
{
  const int stride = gridDim.x * blockDim.x;
  const int tid = blockIdx.x * blockDim.x + threadIdx.x;

  for (int i = tid; i < H3_*H_; i += stride) whh_h[i] = (_Float16)w_hh[i];
  for (int i = tid; i < H3_*224; i += stride) {
    int r = i / 224, c = i - r*224;
    wih_h[i] = (_Float16)(c < P_ ? w_ih[r*P_ + c] : 0.f);  // zero-pad K to 224
  }
  for (int i = tid; i < V_*P_; i += stride) prog_h[i] = (_Float16)prog_emb[i];
  for (int i = tid; i < NW_*B_; i += stride) {
    int w = i / B_, b = i - w*B_;
    int word = instr[(1+w)*B_ + b];
    float e0 = gate_emb[word*2], e1 = gate_emb[word*2+1];
    float m = fmaxf(e0, e1);
    float a = __expf(e0-m), c = __expf(e1-m);
    float inv = 1.f/(a+c);
    g01[i*2] = a*inv; g01[i*2+1] = c*inv;
  }
  for (int i = tid; i < B_*L_; i += stride) {
    int b = i / L_, l = i - b*L_;
    out[OUT1_OFF + i] = (float)tacts[(1+l)*B_ + b];
  }
}

// ---------------------------------------------------------------------------
// gi_gemm: giv[v][n] = program_emb[v] @ w_ih.T + b_ih   (vocab-wide, once)
// ---------------------------------------------------------------------------
__global__ __launch_bounds__(256) void gi_gemm(
    const _Float16* __restrict__ prog_h, const _Float16* __restrict__ wih_h,
    const float* __restrict__ b_ih, float* __restrict__ giv)
{
  __shared__ _Float16 pA[16][232];
  const int tid = threadIdx.x;
  const int v0 = blockIdx.x * 16;
  const int n0 = blockIdx.y * 64;

  for (int i = tid; i < 16*224; i += 256) {
    int r = i / 224, c = i - r*224;
    int v = v0 + r;
    _Float16 val = (_Float16)0.f;
    if (v < V_ && c < P_) val = prog_h[v*P_ + c];
    pA[r][c] = val;
  }
  __syncthreads();

  const int wave = tid >> 6, lane = tid & 63;
  const int m = lane & 15, kg = lane >> 4;
  const int n_t = n0 + wave*16;
  floatx4 acc = {0.f, 0.f, 0.f, 0.f};
  #pragma unroll
  for (int ks = 0; ks < 7; ++ks) {
    const int kk = ks*32 + kg*8;
    half8 av = *(const half8*)&pA[m][kk];
    half8 bv = *(const half8*)&wih_h[(n_t + m)*224 + kk];
    acc = __builtin_amdgcn_mfma_f32_16x16x32_f16(av, bv, acc, 0, 0, 0);
  }
  const int nn = n_t + (lane & 15);
  const float bias = b_ih[nn];
  #pragma unroll
  for (int r = 0; r < 4; ++r) {
    int mm = v0 + kg*4 + r;
    if (mm < V_) giv[(size_t)mm*H3_ + nn] = acc[r] + bias;
  }
}

// ---------------------------------------------------------------------------
// steps16: 16 blocks x 16 batch each; all 30 steps private to the block.
// h (f32 + f16 copy), S coefficients, keys all LDS-resident. w_hh streams
// from L2 each step (884 KB/block, L2-resident). No inter-block traffic.
// Per wave per step: scores MFMA (4) + gh GEMM (108 MFMA, 48-col chunk)
// with GRU epilogue fused in-register.
// ---------------------------------------------------------------------------
__global__ __launch_bounds__(512, 1) void steps16_kernel(
    float* __restrict__ S_buf,
    const _Float16* __restrict__ whh_h, const float* __restrict__ giv,
    const float* __restrict__ g01, const float* __restrict__ keys,
    const float* __restrict__ b_hh, const int* __restrict__ instr)
{
  __shared__ float    hF[16][384];     // h, f32 (row 1536B, 16B-aligned)
  __shared__ _Float16 hT[16][392];     // h, f16 MFMA copy (pad -> 2-way max)
  __shared__ _Float16 keysh[64][136];  // keys f16, rows 50..63 zero
  __shared__ float    Srow[16][50][12];
  __shared__ float    sc[2][16][68];   // scores -> softmax p (in place)
  __shared__ float    nv[16][12];
  __shared__ float    bhh_l[H3_];
  __shared__ int      wordid[16];
  __shared__ float    g0s[16], g1s[16];

  const int bid  = blockIdx.x;
  const int b0   = bid * 16;
  const int tid  = threadIdx.x;
  const int wave = tid >> 6;
  const int lane = tid & 63;
  const int m_   = lane & 15;
  const int kg   = lane >> 4;

  // ---- one-time init ----
  for (int i = tid; i < 64*128; i += 512) {
    int l = i >> 7, k = i & 127;
    keysh[l][k] = (l < L_) ? (_Float16)keys[l*128 + k] : (_Float16)0.f;
  }
  for (int i = tid; i < 16*384; i += 512) {
    int k = i % 384;
    hF[i / 384][k] = keys[k & 127];    // h0 = tile(scratch_keys[0], NP)
  }
  for (int i = tid; i < 16*600; i += 512)
    Srow[i/600][(i%600)/12][i%12] = ((i % 12) == 0) ? 1.f : 0.f;
  for (int i = tid; i < H3_; i += 512) bhh_l[i] = b_hh[i];
  __syncthreads();

  for (int t = 0; t < 30; ++t) {
    const int widx = t / 3;

    if ((t % 3) == 0 && tid < 16) {
      wordid[tid] = instr[(1+widx)*B_ + b0 + tid];
      g0s[tid] = g01[(widx*B_ + b0 + tid)*2 + 0];
      g1s[tid] = g01[(widx*B_ + b0 + tid)*2 + 1];
    }
    // stage hT (f32 -> f16)
    for (int i = tid; i < 16*96; i += 512) {
      int bl = i / 96, k4 = (i - bl*96)*4;
      float4 v = *(const float4*)&hF[bl][k4];
      half4_t hv = {(_Float16)v.x, (_Float16)v.y, (_Float16)v.z, (_Float16)v.w};
      *(half4_t*)&hT[bl][k4] = hv;
    }
    __syncthreads();

    // ---- attention scores via MFMA: waves 0-3 read_p, 4-7 write_p ----
    {
      const int type = wave >> 2;
      const int nt   = wave & 3;
      const int off  = 128 + type*128;
      floatx4 acc = {0.f, 0.f, 0.f, 0.f};
      #pragma unroll
      for (int ks = 0; ks < 4; ++ks) {
        const int kk = ks*32 + kg*8;
        half8 av = *(const half8*)&hT[m_][off + kk];
        half8 bv = *(const half8*)&keysh[nt*16 + m_][kk];
        acc = __builtin_amdgcn_mfma_f32_16x16x32_f16(av, bv, acc, 0, 0, 0);
      }
      #pragma unroll
      for (int r = 0; r < 4; ++r) sc[type][kg*4 + r][nt*16 + m_] = acc[r];
    }
    __syncthreads();

    // ---- softmax: 32 rows (type,b), 4 per wave ----
    #pragma unroll
    for (int q = 0; q < 4; ++q) {
      const int row = wave*4 + q;
      const int ty = row >> 4, b = row & 15;
      float val = (lane < L_) ? sc[ty][b][lane] : -1e30f;
      float mx = val;
      #pragma unroll
      for (int off = 32; off; off >>= 1) mx = fmaxf(mx, __shfl_xor(mx, off));
      float e = (lane < L_) ? __expf(val - mx) : 0.f;
      float sm = e;
      #pragma unroll
      for (int off = 32; off; off >>= 1) sm += __shfl_xor(sm, off);
      if (lane < L_) sc[ty][b][lane] = e / sm;
    }
    __syncthreads();

    // ---- rv + nv (176 threads) ----
    if (tid < 176) {
      const int b = tid / 11, j = tid - b*11;
      float rv = 0.f;
      #pragma unroll 5
      for (int l = 0; l < L_; ++l) rv += sc[0][b][l] * Srow[b][l][j];
      nv[b][j] = g1s[b]*rv + ((j == 1 + widx) ? g0s[b] : 0.f);
    }
    __syncthreads();

    // ---- S update (in place) ----
    for (int i = tid; i < 16*550; i += 512) {
      const int b = i / 550, r2 = i - b*550;
      const int l = r2 / 11, j = r2 - l*11;
      const float wm = sc[1][b][l];
      Srow[b][l][j] = wm*nv[b][j] + (1.f - wm)*Srow[b][l][j];
    }

    // ---- gh GEMM (48-col chunk per wave) + fused GRU epilogue ----
    {
      const int nb = wave * 48;
      #pragma unroll
      for (int nt = 0; nt < 3; ++nt) {
        const int kcol = nb + nt*16 + m_;
        const _Float16* __restrict__ wR = whh_h + (size_t)kcol*H_;
        const _Float16* __restrict__ wZ = wR + (size_t)384*H_;
        const _Float16* __restrict__ wN = wR + (size_t)768*H_;
        floatx4 aR = {0.f,0.f,0.f,0.f}, aZ = {0.f,0.f,0.f,0.f}, aN = {0.f,0.f,0.f,0.f};
        #pragma unroll
        for (int ks = 0; ks < 12; ++ks) {
          const int kk = ks*32 + kg*8;
          half8 av = *(const half8*)&hT[m_][kk];
          aR = __builtin_amdgcn_mfma_f32_16x16x32_f16(av, *(const half8*)&wR[kk], aR, 0, 0, 0);
          aZ = __builtin_amdgcn_mfma_f32_16x16x32_f16(av, *(const half8*)&wZ[kk], aZ, 0, 0, 0);
          aN = __builtin_amdgcn_mfma_f32_16x16x32_f16(av, *(const half8*)&wN[kk], aN, 0, 0, 0);
        }
        const float bR = bhh_l[kcol], bZ = bhh_l[384 + kcol], bN = bhh_l[768 + kcol];
        #pragma unroll
        for (int r = 0; r < 4; ++r) {
          const int b = kg*4 + r;
          const float* __restrict__ gi = giv + (size_t)wordid[b]*H3_ + kcol;
          const float ghr = aR[r] + bR;
          const float ghz = aZ[r] + bZ;
          const float ghn = aN[r] + bN;
          const float rg = 1.f/(1.f + __expf(-(gi[0]   + ghr)));
          const float z  = 1.f/(1.f + __expf(-(gi[384] + ghz)));
          const float x2 = gi[768] + rg*ghn;
          const float nn = 2.f/(1.f + __expf(-2.f*x2)) - 1.f;   // tanh
          const float hold = hF[b][kcol];
          const float hnew = (1.f - z)*nn + z*hold;
          hF[b][kcol] = g0s[b]*hold + g1s[b]*hnew;
        }
      }
    }
    __syncthreads();
  }

  // spill S coefficients for the epilogue kernels
  for (int i = tid; i < 16*600; i += 512) {
    const int bl = i / 600, r2 = i - bl*600;
    S_buf[(size_t)(b0 + bl)*600 + r2] = Srow[bl][r2/12][r2%12];
  }
}

// ---------------------------------------------------------------------------
// lse: per (b,l) log-sum-exp over the 1000-v reconstruction.
// ---------------------------------------------------------------------------
__global__ __launch_bounds__(512) void lse_kernel(
    const float* __restrict__ S_buf, const float* __restrict__ prim_emb,
    const float* __restrict__ iv_g, const int* __restrict__ instr,
    float* __restrict__ ls_buf)
{
  __shared__ float prim[10][1000];
  __shared__ float iv[1000];
  __shared__ float Sr[50][12];
  __shared__ int wds[10];

  const int b = blockIdx.x;
  const int tid = threadIdx.x;

  if (tid < 10) wds[tid] = instr[(1+tid)*B_ + b];
  for (int i = tid; i < 600; i += 512) Sr[i/12][i%12] = S_buf[(size_t)b*600 + i];
  __syncthreads();
  for (int wi = 0; wi < 10; ++wi) {
    const float4* __restrict__ src = (const float4*)(prim_emb + (size_t)wds[wi]*V_);
    for (int i = tid; i < 250; i += 512) ((float4*)prim[wi])[i] = src[i];
  }
  for (int i = tid; i < 250; i += 512) ((float4*)iv)[i] = ((const float4*)iv_g)[i];
  __syncthreads();

  const int wave = tid >> 6, lane = tid & 63;
  for (int l = wave; l < L_; l += 8) {
    float c0 = Sr[l][0];
    float cw[10];
    #pragma unroll
    for (int wi = 0; wi < 10; ++wi) cw[wi] = Sr[l][1+wi];
    float sv[16];
    float mx = -1e30f;
    #pragma unroll
    for (int j = 0; j < 16; ++j) {
      int v = lane + 64*j;
      float s = -1e30f;
      if (v < V_) {
        s = c0 * iv[v];
        #pragma unroll
        for (int wi = 0; wi < 10; ++wi) s += cw[wi]*prim[wi][v];
      }
      sv[j] = s;
      mx = fmaxf(mx, s);
    }
    #pragma unroll
    for (int off = 32; off; off >>= 1) mx = fmaxf(mx, __shfl_xor(mx, off));
    float se = 0.f;
    #pragma unroll
    for (int j = 0; j < 16; ++j) {
      int v = lane + 64*j;
      if (v < V_) se += __expf(sv[j] - mx);
    }
    #pragma unroll
    for (int off = 32; off; off >>= 1) se += __shfl_xor(se, off);
    if (lane == 0) ls_buf[b*L_ + l] = mx + __logf(se);
  }
}

// ---------------------------------------------------------------------------
// write: per (v-chunk of 125, b) block computes sv - lse and stores a
// contiguous 25 KB region (fully coalesced).
// ---------------------------------------------------------------------------
__global__ __launch_bounds__(256) void write_kernel(
    const float* __restrict__ S_buf, const float* __restrict__ prim_emb,
    const float* __restrict__ iv_g, const float* __restrict__ ls_buf,
    const int* __restrict__ instr, float* __restrict__ out)
{
  __shared__ float SrT[11][52];
  __shared__ float lss[52];
  __shared__ float primc[10][128];
  __shared__ float ivc[128];
  __shared__ int wds[10];

  const int cx = blockIdx.x;      // 0..7
  const int b  = blockIdx.y;      // 0..255
  const int v0 = cx * 125;
  const int tid = threadIdx.x;

  if (tid < 10) wds[tid] = instr[(1+tid)*B_ + b];
  if (tid < 50) lss[tid] = ls_buf[b*L_ + tid];
  for (int i = tid; i < 550; i += 256) {
    int l = i / 11, j = i - l*11;
    SrT[j][l] = S_buf[(size_t)b*600 + l*12 + j];
  }
  for (int i = tid; i < 125; i += 256) ivc[i] = iv_g[v0 + i];
  __syncthreads();
  for (int i = tid; i < 1250; i += 256) {
    int wi = i / 125, j = i - wi*125;
    primc[wi][j] = prim_emb[(size_t)wds[wi]*V_ + v0 + j];
  }
  __syncthreads();

  float* __restrict__ dst = out + (size_t)b*50000 + (size_t)v0*50;
  for (int e = tid; e < 125*50; e += 256) {
    const int v = e / 50, l = e - v*50;
    float s = SrT[0][l]*ivc[v];
    #pragma unroll
    for (int wi = 0; wi < 10; ++wi) s += SrT[1+wi][l]*primc[wi][v];
    dst[e] = s - lss[l];
  }
}

// ---------------------------------------------------------------------------
extern "C" void kernel_launch(void* const* d_in, const int* in_sizes, int n_in,
                              void* d_out, int out_size, void* d_ws, size_t ws_size,
                              hipStream_t stream)
{
  (void)in_sizes; (void)n_in; (void)out_size; (void)ws_size;
  const float* gate_emb = (const float*)d_in[0];
  const float* prog_emb = (const float*)d_in[1];
  const float* prim_emb = (const float*)d_in[2];
  const float* sk       = (const float*)d_in[3];
  const float* iv       = (const float*)d_in[4];
  const float* w_ih     = (const float*)d_in[5];
  const float* w_hh     = (const float*)d_in[6];
  const float* b_ih     = (const float*)d_in[7];
  const float* b_hh     = (const float*)d_in[8];
  const int*   instr    = (const int*)d_in[9];
  const int*   tacts    = (const int*)d_in[10];
  float* out = (float*)d_out;

  float* ws     = (float*)d_ws;
  float* S_buf  = ws;                        // 256*600 f32
  float* g01    = S_buf + B_*600;            // 5120 f32
  float* ls_buf = g01 + NW_*B_*2;            // 256*50 f32
  float* giv    = ls_buf + B_*L_;            // 1000*1152 f32
  _Float16* whh_h  = (_Float16*)(giv + (size_t)V_*H3_);
  _Float16* wih_h  = whh_h + (size_t)H3_*H_;
  _Float16* prog_h = wih_h + (size_t)H3_*224;

  hipLaunchKernelGGL(prep_kernel, dim3(1024), dim3(256), 0, stream,
      gate_emb, prog_emb, w_ih, w_hh, instr, tacts,
      g01, whh_h, wih_h, prog_h, out);

  hipLaunchKernelGGL(gi_gemm, dim3(63, 18), dim3(256), 0, stream,
      prog_h, wih_h, b_ih, giv);

  hipLaunchKernelGGL(steps16_kernel, dim3(16), dim3(512), 0, stream,
      S_buf, whh_h, giv, g01, sk, b_hh, instr);

  hipLaunchKernelGGL(lse_kernel, dim3(256), dim3(512), 0, stream,
      S_buf, prim_emb, iv, instr, ls_buf);

  hipLaunchKernelGGL(write_kernel, dim3(8, 256), dim3(256), 0, stream,
      S_buf, prim_emb, iv, ls_buf, instr, out);
}